// Round 2
// baseline (255.406 us; speedup 1.0000x reference)
//
#include <hip/hip_runtime.h>

#define TPB 512
#define ROWS 32

// One block: 32 node rows end-to-end, 512 threads, 66.8 KB LDS -> 2 blocks/CU
// = 16 waves/CU (4/SIMD), double R1's occupancy. Grid 512 = exactly 2/CU.
//   stage1: h1 = relu(X@W1n+b1n)          (32x128)@(128x256), tile 2r x 8c
//   stage2: h  = h1@W2n+b2n -> h_out+LDS  (32x256)@(256x128), tile 2r x 4c
//   stage3: t1acc = h@(W1e_t+W1e_b)+b1e   (32x128)@(128x128), tile 2r x 4c (regs)
//   stage4: e[r] = (relu(t1).w2e+b2e)/2048 -- in-register shfl_xor reduce
//   stage5: edge[r, :] = e[r], one float4/thread/row (coalesced 1KB/wave)
__global__ __launch_bounds__(TPB, 4)
void fused_node_edge(const float* __restrict__ x,
                     const float* __restrict__ w1n, const float* __restrict__ b1n,
                     const float* __restrict__ w2n, const float* __restrict__ b2n,
                     const float* __restrict__ w1e, const float* __restrict__ b1e,
                     const float* __restrict__ w2e, const float* __restrict__ b2e,
                     float* __restrict__ h_out, float* __restrict__ edge_out)
{
    __shared__ float xs[ROWS * 128];    // 16 KB
    __shared__ float h1s[ROWS * 260];   // 33.3 KB, stride 260: rows land on distinct banks
    __shared__ float hhs[ROWS * 132];   // 16.9 KB
    __shared__ float es[ROWS];

    const int t = threadIdx.x;
    const int row0 = blockIdx.x * ROWS;
    const int lane31 = t & 31;
    const int r0 = (t >> 5) * 2;        // 16 row-groups of 2 rows

    // ---- load X tile: 32x128 floats = 1024 float4, 2 per thread ----
    {
        const float4* __restrict__ x4 = (const float4*)(x + (size_t)row0 * 128);
        float4* xs4 = (float4*)xs;
        xs4[t] = x4[t];
        xs4[t + TPB] = x4[t + TPB];
    }
    __syncthreads();

    // ---- stage 1: h1 = relu(X @ W1n + b1n), tile 2 rows x 8 cols ----
    {
        const int c0 = lane31 * 8;                     // 32 col-groups of 8
        const float4* __restrict__ w4 = (const float4*)w1n;
        const float4 bA = ((const float4*)b1n)[lane31 * 2];
        const float4 bB = ((const float4*)b1n)[lane31 * 2 + 1];
        float acc[2][8];
#pragma unroll
        for (int i = 0; i < 2; ++i) {
            acc[i][0] = bA.x; acc[i][1] = bA.y; acc[i][2] = bA.z; acc[i][3] = bA.w;
            acc[i][4] = bB.x; acc[i][5] = bB.y; acc[i][6] = bB.z; acc[i][7] = bB.w;
        }
#pragma unroll 4
        for (int d = 0; d < 128; ++d) {
            const float4 wa = w4[d * 64 + lane31 * 2];
            const float4 wb = w4[d * 64 + lane31 * 2 + 1];
            const float x0 = xs[r0 * 128 + d];
            const float x1 = xs[(r0 + 1) * 128 + d];
            const float w[8] = {wa.x, wa.y, wa.z, wa.w, wb.x, wb.y, wb.z, wb.w};
#pragma unroll
            for (int j = 0; j < 8; ++j) {
                acc[0][j] = fmaf(x0, w[j], acc[0][j]);
                acc[1][j] = fmaf(x1, w[j], acc[1][j]);
            }
        }
#pragma unroll
        for (int i = 0; i < 2; ++i) {
            float4 lo = make_float4(fmaxf(acc[i][0], 0.f), fmaxf(acc[i][1], 0.f),
                                    fmaxf(acc[i][2], 0.f), fmaxf(acc[i][3], 0.f));
            float4 hi = make_float4(fmaxf(acc[i][4], 0.f), fmaxf(acc[i][5], 0.f),
                                    fmaxf(acc[i][6], 0.f), fmaxf(acc[i][7], 0.f));
            *(float4*)&h1s[(r0 + i) * 260 + c0] = lo;
            *(float4*)&h1s[(r0 + i) * 260 + c0 + 4] = hi;
        }
    }
    __syncthreads();

    // ---- stage 2: h = h1 @ W2n + b2n, tile 2 rows x 4 cols ----
    {
        const int c0 = lane31 * 4;                     // 32 col-groups of 4
        const float4* __restrict__ w4 = (const float4*)w2n;
        const float4 b = ((const float4*)b2n)[lane31];
        float acc[2][4];
#pragma unroll
        for (int i = 0; i < 2; ++i) {
            acc[i][0] = b.x; acc[i][1] = b.y; acc[i][2] = b.z; acc[i][3] = b.w;
        }
#pragma unroll 4
        for (int j = 0; j < 256; ++j) {
            const float4 wa = w4[j * 32 + lane31];
            const float h0 = h1s[r0 * 260 + j];
            const float h1v = h1s[(r0 + 1) * 260 + j];
            acc[0][0] = fmaf(h0, wa.x, acc[0][0]);
            acc[0][1] = fmaf(h0, wa.y, acc[0][1]);
            acc[0][2] = fmaf(h0, wa.z, acc[0][2]);
            acc[0][3] = fmaf(h0, wa.w, acc[0][3]);
            acc[1][0] = fmaf(h1v, wa.x, acc[1][0]);
            acc[1][1] = fmaf(h1v, wa.y, acc[1][1]);
            acc[1][2] = fmaf(h1v, wa.z, acc[1][2]);
            acc[1][3] = fmaf(h1v, wa.w, acc[1][3]);
        }
#pragma unroll
        for (int i = 0; i < 2; ++i) {
            const float4 v = make_float4(acc[i][0], acc[i][1], acc[i][2], acc[i][3]);
            *(float4*)(h_out + (size_t)(row0 + r0 + i) * 128 + c0) = v;
            *(float4*)&hhs[(r0 + i) * 132 + c0] = v;
        }
    }
    __syncthreads();

    // ---- stage 3: t1acc = h @ (W1e_top + W1e_bot) + b1e, tile 2 rows x 4 cols ----
    float acc3[2][4];
    {
        const float4* __restrict__ w4 = (const float4*)w1e;
        const float4 b = ((const float4*)b1e)[lane31];
#pragma unroll
        for (int i = 0; i < 2; ++i) {
            acc3[i][0] = b.x; acc3[i][1] = b.y; acc3[i][2] = b.z; acc3[i][3] = b.w;
        }
#pragma unroll 2
        for (int l = 0; l < 128; ++l) {
            const float4 wa = w4[l * 32 + lane31];
            const float4 wb = w4[(l + 128) * 32 + lane31];
            const float w0 = wa.x + wb.x, w1 = wa.y + wb.y;
            const float w2 = wa.z + wb.z, w3 = wa.w + wb.w;
            const float h0 = hhs[r0 * 132 + l];
            const float h1v = hhs[(r0 + 1) * 132 + l];
            acc3[0][0] = fmaf(h0, w0, acc3[0][0]);
            acc3[0][1] = fmaf(h0, w1, acc3[0][1]);
            acc3[0][2] = fmaf(h0, w2, acc3[0][2]);
            acc3[0][3] = fmaf(h0, w3, acc3[0][3]);
            acc3[1][0] = fmaf(h1v, w0, acc3[1][0]);
            acc3[1][1] = fmaf(h1v, w1, acc3[1][1]);
            acc3[1][2] = fmaf(h1v, w2, acc3[1][2]);
            acc3[1][3] = fmaf(h1v, w3, acc3[1][3]);
        }
    }

    // ---- stage 4: e[r] = (relu(t1) . w2e + b2e) / 2048, in-register ----
    {
        const float4 wv = ((const float4*)w2e)[lane31];  // lanes 0..31 cover all 128
        float p0 = fmaxf(acc3[0][0], 0.f) * wv.x + fmaxf(acc3[0][1], 0.f) * wv.y
                 + fmaxf(acc3[0][2], 0.f) * wv.z + fmaxf(acc3[0][3], 0.f) * wv.w;
        float p1 = fmaxf(acc3[1][0], 0.f) * wv.x + fmaxf(acc3[1][1], 0.f) * wv.y
                 + fmaxf(acc3[1][2], 0.f) * wv.z + fmaxf(acc3[1][3], 0.f) * wv.w;
#pragma unroll
        for (int off = 16; off >= 1; off >>= 1) {
            p0 += __shfl_xor(p0, off, 32);
            p1 += __shfl_xor(p1, off, 32);
        }
        if (lane31 == 0) {
            const float bb = b2e[0];
            es[r0]     = (p0 + bb) * (1.0f / 2048.0f);
            es[r0 + 1] = (p1 + bb) * (1.0f / 2048.0f);
        }
    }
    __syncthreads();

    // ---- stage 5: edge broadcast, one float4/thread/row (512 f4 = full row) ----
    {
        float4* __restrict__ e4 = (float4*)(edge_out + (size_t)row0 * 2048);
#pragma unroll 4
        for (int r = 0; r < ROWS; ++r) {
            const float ev = es[r];
            e4[r * 512 + t] = make_float4(ev, ev, ev, ev);
        }
    }
}

extern "C" void kernel_launch(void* const* d_in, const int* in_sizes, int n_in,
                              void* d_out, int out_size, void* d_ws, size_t ws_size,
                              hipStream_t stream) {
    const float* x   = (const float*)d_in[0];
    const float* w1n = (const float*)d_in[1];
    const float* b1n = (const float*)d_in[2];
    const float* w2n = (const float*)d_in[3];
    const float* b2n = (const float*)d_in[4];
    const float* w1e = (const float*)d_in[5];
    const float* b1e = (const float*)d_in[6];
    const float* w2e = (const float*)d_in[7];
    const float* b2e = (const float*)d_in[8];

    float* h_out    = (float*)d_out;                              // (8,2048,128)
    float* edge_out = (float*)d_out + (size_t)8 * 2048 * 128;     // (8,2048,2048)

    fused_node_edge<<<dim3(512), dim3(TPB), 0, stream>>>(
        x, w1n, b1n, w2n, b2n, w1e, b1e, w2e, b2e, h_out, edge_out);
}

// Round 4
// 184.295 us; speedup vs baseline: 1.3859x; 1.3859x over previous
//
#include <hip/hip_runtime.h>

// Shapes: N=8, M=2048 -> 16384 rows; D=128, L=128.
// out0 h: (16384,128) fp32; out1 edge: (8,2048,2048) = e[row] broadcast.
//
// R2 post-mortem: fp32 VALU path was L1-BW-bound on 16x-redundant weight
// loads (12 MB/CU through ~64B/cyc L1 ~= 82us) + ~35us write-burst drain.
// R3: bf16 MFMA (weights read ONCE per block from L2-resident bf16
// transposed copies in d_ws) -> compute ~5us, kernel becomes edge-write-
// drain bound (~136MB).
// R4: fix nontemporal-store builtin typing (needs ext_vector_type, not
// HIP_vector_type struct).

typedef short short8 __attribute__((ext_vector_type(8)));
typedef float floatx4 __attribute__((ext_vector_type(4)));

__device__ __forceinline__ short f2bf(float f) {
    union { float f; unsigned u; } v; v.f = f;
    unsigned r = v.u + 0x7fffu + ((v.u >> 16) & 1u);   // RNE
    return (short)(r >> 16);
}

// d_ws layout (shorts): W1T[256][128] at 0      (w1n^T,  64KB)
//                       W2T[128][256] at 32768  (w2n^T,  64KB)
//                       WET[128][128] at 65536  ((w1e_top+w1e_bot)^T, 32KB)
// Requires ws_size >= 163840 bytes.
__global__ __launch_bounds__(256)
void prep_weights(const float* __restrict__ w1n, const float* __restrict__ w2n,
                  const float* __restrict__ w1e, short* __restrict__ ws)
{
    const int id = blockIdx.x * 256 + threadIdx.x;   // 0..81919
    if (id < 32768) {                                // W1T[n][k] = w1n[k][n]
        const int n = id >> 7, k = id & 127;
        ws[id] = f2bf(w1n[k * 256 + n]);
    } else if (id < 65536) {                         // W2T[n][k] = w2n[k][n]
        const int j = id - 32768;
        const int n = j >> 8, k = j & 255;
        ws[id] = f2bf(w2n[k * 128 + n]);
    } else {                                         // WET[n][k] = sum of halves
        const int j = id - 65536;
        const int n = j >> 7, k = j & 127;
        ws[id] = f2bf(w1e[k * 128 + n] + w1e[(k + 128) * 128 + n]);
    }
}

#define TPB 256
#define ROWS 32
#define XS_STRIDE 136   // 128 + 8 pad (bf16) -> b128 row reads ~conflict-free
#define H1_STRIDE 264   // 256 + 8 pad

// MFMA 16x16x32 bf16 lane mapping (HW-verified per docs):
//   A: lane holds A[m = lane&15][k = (lane>>4)*8 + j], j=0..7 (contiguous k)
//   B: lane holds B[k = (lane>>4)*8 + j][n = lane&15]         (contiguous k)
//   C/D: reg r holds D[row = (lane>>4)*4 + r][col = lane&15]
__global__ __launch_bounds__(TPB, 2)
void fused_node_edge(const float* __restrict__ x,
                     const float* __restrict__ b1n, const float* __restrict__ b2n,
                     const float* __restrict__ b1e,
                     const float* __restrict__ w2e, const float* __restrict__ b2e,
                     const short* __restrict__ wt,
                     float* __restrict__ h_out, float* __restrict__ edge_out)
{
    __shared__ short xs[ROWS * XS_STRIDE];    // x tile, bf16 (17.4 KB)
    __shared__ short h1s[ROWS * H1_STRIDE];   // relu(h1), bf16 (16.9 KB)
    __shared__ short hbs[ROWS * XS_STRIDE];   // h, bf16 (17.4 KB)
    __shared__ float partial[4][ROWS];
    __shared__ float es[ROWS];

    const int t = threadIdx.x;
    const int w = t >> 6;          // wave 0..3
    const int l = t & 63;
    const int l15 = l & 15;
    const int quad = l >> 4;
    const int row0 = blockIdx.x * ROWS;

    // ---- stage x: load 32x128 fp32 tile, convert to bf16 in LDS ----
    {
        const float4* __restrict__ x4 = (const float4*)(x + (size_t)row0 * 128);
#pragma unroll
        for (int i = 0; i < 4; ++i) {
            const int fi = t + i * TPB;            // 1024 float4 total
            const float4 v = x4[fi];
            const int row = fi >> 5, col = (fi & 31) * 4;
            short4 s;
            s.x = f2bf(v.x); s.y = f2bf(v.y); s.z = f2bf(v.z); s.w = f2bf(v.w);
            *(short4*)&xs[row * XS_STRIDE + col] = s;
        }
    }
    __syncthreads();

    // ---- stage 1: h1 = relu(X @ W1n + b1n)   (32x128)@(128x256) ----
    // wave w owns col-tiles {4w..4w+3}, both row-tiles. 32 MFMA/wave.
    {
        short8 a1[2][4];
#pragma unroll
        for (int rt = 0; rt < 2; ++rt)
#pragma unroll
            for (int k = 0; k < 4; ++k)
                a1[rt][k] = *(const short8*)&xs[(rt * 16 + l15) * XS_STRIDE + k * 32 + quad * 8];

        floatx4 acc1[2][4];
#pragma unroll
        for (int ci = 0; ci < 4; ++ci) {
            const int ct = 4 * w + ci;
            const float b = b1n[ct * 16 + l15];
            acc1[0][ci] = (floatx4){b, b, b, b};
            acc1[1][ci] = (floatx4){b, b, b, b};
#pragma unroll
            for (int k = 0; k < 4; ++k) {
                const short8 bf = *(const short8*)(wt + (ct * 16 + l15) * 128 + k * 32 + quad * 8);
                acc1[0][ci] = __builtin_amdgcn_mfma_f32_16x16x32_bf16(a1[0][k], bf, acc1[0][ci], 0, 0, 0);
                acc1[1][ci] = __builtin_amdgcn_mfma_f32_16x16x32_bf16(a1[1][k], bf, acc1[1][ci], 0, 0, 0);
            }
        }
#pragma unroll
        for (int ci = 0; ci < 4; ++ci) {
            const int ct = 4 * w + ci;
#pragma unroll
            for (int rt = 0; rt < 2; ++rt)
#pragma unroll
                for (int r = 0; r < 4; ++r) {
                    const int row = rt * 16 + quad * 4 + r;
                    h1s[row * H1_STRIDE + ct * 16 + l15] = f2bf(fmaxf(acc1[rt][ci][r], 0.f));
                }
        }
    }
    __syncthreads();

    // ---- stage 2: h = h1 @ W2n + b2n   (32x256)@(256x128) ----
    // wave w owns col-tiles {2w, 2w+1}, both row-tiles. 32 MFMA/wave.
    {
        short8 a2[2][8];
#pragma unroll
        for (int rt = 0; rt < 2; ++rt)
#pragma unroll
            for (int k = 0; k < 8; ++k)
                a2[rt][k] = *(const short8*)&h1s[(rt * 16 + l15) * H1_STRIDE + k * 32 + quad * 8];

        const short* __restrict__ W2T = wt + 32768;
        floatx4 acc2[2][2];
#pragma unroll
        for (int ci = 0; ci < 2; ++ci) {
            const int ct = 2 * w + ci;
            const float b = b2n[ct * 16 + l15];
            acc2[0][ci] = (floatx4){b, b, b, b};
            acc2[1][ci] = (floatx4){b, b, b, b};
#pragma unroll
            for (int k = 0; k < 8; ++k) {
                const short8 bf = *(const short8*)(W2T + (ct * 16 + l15) * 256 + k * 32 + quad * 8);
                acc2[0][ci] = __builtin_amdgcn_mfma_f32_16x16x32_bf16(a2[0][k], bf, acc2[0][ci], 0, 0, 0);
                acc2[1][ci] = __builtin_amdgcn_mfma_f32_16x16x32_bf16(a2[1][k], bf, acc2[1][ci], 0, 0, 0);
            }
        }
#pragma unroll
        for (int ci = 0; ci < 2; ++ci) {
            const int ct = 2 * w + ci;
#pragma unroll
            for (int rt = 0; rt < 2; ++rt)
#pragma unroll
                for (int r = 0; r < 4; ++r) {
                    const int row = rt * 16 + quad * 4 + r;
                    const float v = acc2[rt][ci][r];
                    h_out[(size_t)(row0 + row) * 128 + ct * 16 + l15] = v;
                    hbs[row * XS_STRIDE + ct * 16 + l15] = f2bf(v);
                }
        }
    }
    __syncthreads();

    // ---- stage 3+4: t1 = relu(h @ WE + b1e); e = (t1 . w2e + b2e)/2048 ----
    {
        short8 a3[2][4];
#pragma unroll
        for (int rt = 0; rt < 2; ++rt)
#pragma unroll
            for (int k = 0; k < 4; ++k)
                a3[rt][k] = *(const short8*)&hbs[(rt * 16 + l15) * XS_STRIDE + k * 32 + quad * 8];

        const short* __restrict__ WET = wt + 65536;
        float p[2][4] = {{0.f, 0.f, 0.f, 0.f}, {0.f, 0.f, 0.f, 0.f}};
#pragma unroll
        for (int ci = 0; ci < 2; ++ci) {
            const int ct = 2 * w + ci;
            const float b = b1e[ct * 16 + l15];
            floatx4 acc3a = (floatx4){b, b, b, b};
            floatx4 acc3b = (floatx4){b, b, b, b};
#pragma unroll
            for (int k = 0; k < 4; ++k) {
                const short8 bf = *(const short8*)(WET + (ct * 16 + l15) * 128 + k * 32 + quad * 8);
                acc3a = __builtin_amdgcn_mfma_f32_16x16x32_bf16(a3[0][k], bf, acc3a, 0, 0, 0);
                acc3b = __builtin_amdgcn_mfma_f32_16x16x32_bf16(a3[1][k], bf, acc3b, 0, 0, 0);
            }
            const float wv = w2e[ct * 16 + l15];
#pragma unroll
            for (int r = 0; r < 4; ++r) {
                p[0][r] += fmaxf(acc3a[r], 0.f) * wv;
                p[1][r] += fmaxf(acc3b[r], 0.f) * wv;
            }
        }
        // reduce over the 16 cols held across lanes (xor<16 stays in quad)
#pragma unroll
        for (int off = 8; off >= 1; off >>= 1)
#pragma unroll
            for (int rt = 0; rt < 2; ++rt)
#pragma unroll
                for (int r = 0; r < 4; ++r)
                    p[rt][r] += __shfl_xor(p[rt][r], off, 64);
        if (l15 == 0) {
#pragma unroll
            for (int rt = 0; rt < 2; ++rt)
#pragma unroll
                for (int r = 0; r < 4; ++r)
                    partial[w][rt * 16 + quad * 4 + r] = p[rt][r];
        }
    }
    __syncthreads();
    if (t < ROWS) {
        es[t] = (partial[0][t] + partial[1][t] + partial[2][t] + partial[3][t]
                 + b2e[0]) * (1.0f / 2048.0f);
    }
    __syncthreads();

    // ---- stage 5: edge broadcast, 32 rows x 2048 floats, nontemporal ----
    {
        floatx4* __restrict__ e4 = (floatx4*)(edge_out + (size_t)row0 * 2048);
#pragma unroll 4
        for (int r = 0; r < ROWS; ++r) {
            const float ev = es[r];
            const floatx4 vv = (floatx4){ev, ev, ev, ev};
            __builtin_nontemporal_store(vv, &e4[r * 512 + t]);
            __builtin_nontemporal_store(vv, &e4[r * 512 + t + 256]);
        }
    }
}

extern "C" void kernel_launch(void* const* d_in, const int* in_sizes, int n_in,
                              void* d_out, int out_size, void* d_ws, size_t ws_size,
                              hipStream_t stream) {
    const float* x   = (const float*)d_in[0];
    const float* w1n = (const float*)d_in[1];
    const float* b1n = (const float*)d_in[2];
    const float* w2n = (const float*)d_in[3];
    const float* b2n = (const float*)d_in[4];
    const float* w1e = (const float*)d_in[5];
    const float* b1e = (const float*)d_in[6];
    const float* w2e = (const float*)d_in[7];
    const float* b2e = (const float*)d_in[8];

    float* h_out    = (float*)d_out;                              // (8,2048,128)
    float* edge_out = (float*)d_out + (size_t)8 * 2048 * 128;     // (8,2048,2048)
    short* wt       = (short*)d_ws;                               // 160 KB bf16 weights

    prep_weights<<<dim3(320), dim3(256), 0, stream>>>(w1n, w2n, w1e, wt);
    fused_node_edge<<<dim3(512), dim3(TPB), 0, stream>>>(
        x, b1n, b2n, b1e, w2e, b2e, wt, h_out, edge_out);
}

// Round 5
// 182.438 us; speedup vs baseline: 1.4000x; 1.0102x over previous
//
#include <hip/hip_runtime.h>

// Shapes: N=8, M=2048 -> 16384 rows; D=128, L=128.
// out0 h: (16384,128) fp32; out1 edge: (8,2048,2048) = e[row] broadcast.
//
// R4 post-mortem: correct bf16-MFMA version ran ~55-60us (vs ~24us traffic
// floor: 8MB x-read + 8MB h-write + 134MB edge-write @6.3TB/s). Limiter:
// 2 blocks/CU = 8 waves/CU latency-bound 5-barrier pipeline.
// R5: ROWS 32->16, grid 512->1024, LDS 52->17.5KB -> 4 blocks/CU resident
// (16 waves/CU), half the per-block serial depth.

typedef short short8 __attribute__((ext_vector_type(8)));
typedef float floatx4 __attribute__((ext_vector_type(4)));

__device__ __forceinline__ short f2bf(float f) {
    union { float f; unsigned u; } v; v.f = f;
    unsigned r = v.u + 0x7fffu + ((v.u >> 16) & 1u);   // RNE
    return (short)(r >> 16);
}

// d_ws layout (shorts): W1T[256][128] at 0      (w1n^T,  64KB)
//                       W2T[128][256] at 32768  (w2n^T,  64KB)
//                       WET[128][128] at 65536  ((w1e_top+w1e_bot)^T, 32KB)
// Requires ws_size >= 163840 bytes.
__global__ __launch_bounds__(256)
void prep_weights(const float* __restrict__ w1n, const float* __restrict__ w2n,
                  const float* __restrict__ w1e, short* __restrict__ ws)
{
    const int id = blockIdx.x * 256 + threadIdx.x;   // 0..81919
    if (id < 32768) {                                // W1T[n][k] = w1n[k][n]
        const int n = id >> 7, k = id & 127;
        ws[id] = f2bf(w1n[k * 256 + n]);
    } else if (id < 65536) {                         // W2T[n][k] = w2n[k][n]
        const int j = id - 32768;
        const int n = j >> 8, k = j & 255;
        ws[id] = f2bf(w2n[k * 128 + n]);
    } else {                                         // WET[n][k] = sum of halves
        const int j = id - 65536;
        const int n = j >> 7, k = j & 127;
        ws[id] = f2bf(w1e[k * 128 + n] + w1e[(k + 128) * 128 + n]);
    }
}

#define TPB 256
#define ROWS 16
#define XS_STRIDE 136   // 128 + 8 pad (bf16)
#define H1_STRIDE 264   // 256 + 8 pad

// MFMA 16x16x32 bf16 lane mapping (HW-verified per docs):
//   A: lane holds A[m = lane&15][k = (lane>>4)*8 + j], j=0..7
//   B: lane holds B[k = (lane>>4)*8 + j][n = lane&15]
//   C/D: reg r holds D[row = (lane>>4)*4 + r][col = lane&15]
__global__ __launch_bounds__(TPB, 4)
void fused_node_edge(const float* __restrict__ x,
                     const float* __restrict__ b1n, const float* __restrict__ b2n,
                     const float* __restrict__ b1e,
                     const float* __restrict__ w2e, const float* __restrict__ b2e,
                     const short* __restrict__ wt,
                     float* __restrict__ h_out, float* __restrict__ edge_out)
{
    __shared__ short xs[ROWS * XS_STRIDE];    // 4.3 KB
    __shared__ short h1s[ROWS * H1_STRIDE];   // 8.4 KB
    __shared__ short hbs[ROWS * XS_STRIDE];   // 4.3 KB
    __shared__ float partial[4][ROWS];
    __shared__ float es[ROWS];

    const int t = threadIdx.x;
    const int w = t >> 6;          // wave 0..3
    const int l = t & 63;
    const int l15 = l & 15;
    const int quad = l >> 4;
    const int row0 = blockIdx.x * ROWS;

    // ---- load 16x128 fp32 tile, convert to bf16 in LDS ----
    {
        const float4* __restrict__ x4 = (const float4*)(x + (size_t)row0 * 128);
#pragma unroll
        for (int i = 0; i < 2; ++i) {
            const int fi = t + i * TPB;            // 512 float4 total
            const float4 v = x4[fi];
            const int row = fi >> 5, col = (fi & 31) * 4;
            short4 s;
            s.x = f2bf(v.x); s.y = f2bf(v.y); s.z = f2bf(v.z); s.w = f2bf(v.w);
            *(short4*)&xs[row * XS_STRIDE + col] = s;
        }
    }
    __syncthreads();

    // ---- stage 1: h1 = relu(X @ W1n + b1n)   (16x128)@(128x256) ----
    // wave w owns col-tiles {4w..4w+3}. 16 MFMA/wave.
    {
        short8 a1[4];
#pragma unroll
        for (int k = 0; k < 4; ++k)
            a1[k] = *(const short8*)&xs[l15 * XS_STRIDE + k * 32 + quad * 8];

        floatx4 acc1[4];
#pragma unroll
        for (int ci = 0; ci < 4; ++ci) {
            const int ct = 4 * w + ci;
            const float b = b1n[ct * 16 + l15];
            acc1[ci] = (floatx4){b, b, b, b};
#pragma unroll
            for (int k = 0; k < 4; ++k) {
                const short8 bf = *(const short8*)(wt + (ct * 16 + l15) * 128 + k * 32 + quad * 8);
                acc1[ci] = __builtin_amdgcn_mfma_f32_16x16x32_bf16(a1[k], bf, acc1[ci], 0, 0, 0);
            }
        }
#pragma unroll
        for (int ci = 0; ci < 4; ++ci) {
            const int ct = 4 * w + ci;
#pragma unroll
            for (int r = 0; r < 4; ++r)
                h1s[(quad * 4 + r) * H1_STRIDE + ct * 16 + l15] = f2bf(fmaxf(acc1[ci][r], 0.f));
        }
    }
    __syncthreads();

    // ---- stage 2: h = h1 @ W2n + b2n   (16x256)@(256x128) ----
    // wave w owns col-tiles {2w, 2w+1}. 16 MFMA/wave.
    {
        short8 a2[8];
#pragma unroll
        for (int k = 0; k < 8; ++k)
            a2[k] = *(const short8*)&h1s[l15 * H1_STRIDE + k * 32 + quad * 8];

        const short* __restrict__ W2T = wt + 32768;
#pragma unroll
        for (int ci = 0; ci < 2; ++ci) {
            const int ct = 2 * w + ci;
            const float b = b2n[ct * 16 + l15];
            floatx4 acc2 = (floatx4){b, b, b, b};
#pragma unroll
            for (int k = 0; k < 8; ++k) {
                const short8 bf = *(const short8*)(W2T + (ct * 16 + l15) * 256 + k * 32 + quad * 8);
                acc2 = __builtin_amdgcn_mfma_f32_16x16x32_bf16(a2[k], bf, acc2, 0, 0, 0);
            }
#pragma unroll
            for (int r = 0; r < 4; ++r) {
                const int row = quad * 4 + r;
                const float v = acc2[r];
                h_out[(size_t)(row0 + row) * 128 + ct * 16 + l15] = v;
                hbs[row * XS_STRIDE + ct * 16 + l15] = f2bf(v);
            }
        }
    }
    __syncthreads();

    // ---- stage 3+4: t1 = relu(h @ WE + b1e); e = (t1 . w2e + b2e)/2048 ----
    {
        short8 a3[4];
#pragma unroll
        for (int k = 0; k < 4; ++k)
            a3[k] = *(const short8*)&hbs[l15 * XS_STRIDE + k * 32 + quad * 8];

        const short* __restrict__ WET = wt + 65536;
        float p[4] = {0.f, 0.f, 0.f, 0.f};
#pragma unroll
        for (int ci = 0; ci < 2; ++ci) {
            const int ct = 2 * w + ci;
            const float b = b1e[ct * 16 + l15];
            floatx4 acc3 = (floatx4){b, b, b, b};
#pragma unroll
            for (int k = 0; k < 4; ++k) {
                const short8 bf = *(const short8*)(WET + (ct * 16 + l15) * 128 + k * 32 + quad * 8);
                acc3 = __builtin_amdgcn_mfma_f32_16x16x32_bf16(a3[k], bf, acc3, 0, 0, 0);
            }
            const float wv = w2e[ct * 16 + l15];
#pragma unroll
            for (int r = 0; r < 4; ++r)
                p[r] += fmaxf(acc3[r], 0.f) * wv;
        }
        // reduce across the 16 lanes of l15 (xor offsets 1..8 stay in-group)
#pragma unroll
        for (int off = 8; off >= 1; off >>= 1)
#pragma unroll
            for (int r = 0; r < 4; ++r)
                p[r] += __shfl_xor(p[r], off, 64);
        if (l15 == 0) {
#pragma unroll
            for (int r = 0; r < 4; ++r)
                partial[w][quad * 4 + r] = p[r];
        }
    }
    __syncthreads();
    if (t < ROWS) {
        es[t] = (partial[0][t] + partial[1][t] + partial[2][t] + partial[3][t]
                 + b2e[0]) * (1.0f / 2048.0f);
    }
    __syncthreads();

    // ---- stage 5: edge broadcast, 16 rows x 2048 floats, nontemporal ----
    {
        floatx4* __restrict__ e4 = (floatx4*)(edge_out + (size_t)row0 * 2048);
#pragma unroll 4
        for (int r = 0; r < ROWS; ++r) {
            const float ev = es[r];
            const floatx4 vv = (floatx4){ev, ev, ev, ev};
            __builtin_nontemporal_store(vv, &e4[r * 512 + t]);
            __builtin_nontemporal_store(vv, &e4[r * 512 + t + 256]);
        }
    }
}

extern "C" void kernel_launch(void* const* d_in, const int* in_sizes, int n_in,
                              void* d_out, int out_size, void* d_ws, size_t ws_size,
                              hipStream_t stream) {
    const float* x   = (const float*)d_in[0];
    const float* w1n = (const float*)d_in[1];
    const float* b1n = (const float*)d_in[2];
    const float* w2n = (const float*)d_in[3];
    const float* b2n = (const float*)d_in[4];
    const float* w1e = (const float*)d_in[5];
    const float* b1e = (const float*)d_in[6];
    const float* w2e = (const float*)d_in[7];
    const float* b2e = (const float*)d_in[8];

    float* h_out    = (float*)d_out;                              // (8,2048,128)
    float* edge_out = (float*)d_out + (size_t)8 * 2048 * 128;     // (8,2048,2048)
    short* wt       = (short*)d_ws;                               // 160 KB bf16 weights

    prep_weights<<<dim3(320), dim3(256), 0, stream>>>(w1n, w2n, w1e, wt);
    fused_node_edge<<<dim3(1024), dim3(TPB), 0, stream>>>(
        x, b1n, b2n, b1e, w2e, b2e, wt, h_out, edge_out);
}